// Round 6
// baseline (265.758 us; speedup 1.0000x reference)
//
#include <hip/hip_runtime.h>
#include <math.h>

#define SEQ 4096
#define LOG2SEQ 12
#define TOPK 8
#define NB 16
#define ND 128
#define NEGINF (-3.402823466e+38f)

// Pads: PAD2 for float2 arrays (1 per 16 elements), PADF for float arrays.
#define PAD2(i) ((i) + ((i) >> 4))
#define PADF(i) ((i) + ((i) >> 5))

// LDS pitch (floats) for the 64x64 transpose tile: 68*4=272B, 16B-aligned so
// float4 LDS reads are legal; +4 pad rotates banks across rows.
#define TPITCH 68

__device__ __forceinline__ int rev12(int x) {
    return (int)(__brev((unsigned)x) >> (32 - LOG2SEQ));
}

// 64x64 tiled transpose body: in is [R][C], out is [C][R]; both multiples of 64.
// float4 on both global sides; LDS staged as lds[col*TPITCH + row].
__device__ __forceinline__ void transpose64_body(const float* __restrict__ inb,
                                                 float* __restrict__ outb,
                                                 int R, int C) {
    __shared__ float lds[64 * TPITCH];
    const int tid = threadIdx.x;
    const int c0 = blockIdx.x * 64, r0 = blockIdx.y * 64;
    const int q = tid & 15;          // float4 index within 64-wide span
    const int rr = tid >> 4;         // 16 rows per pass
#pragma unroll
    for (int pass = 0; pass < 4; ++pass) {
        const int r = pass * 16 + rr;
        const float4 v =
            *(const float4*)(inb + (size_t)(r0 + r) * C + (c0 + 4 * q));
        const int base = (4 * q) * TPITCH + r;  // scatter: transposed in LDS
        lds[base] = v.x;
        lds[base + TPITCH] = v.y;
        lds[base + 2 * TPITCH] = v.z;
        lds[base + 3 * TPITCH] = v.w;
    }
    __syncthreads();
#pragma unroll
    for (int pass = 0; pass < 4; ++pass) {
        const int c = pass * 16 + rr;  // local output row (= input col)
        const float4 v = *(const float4*)(lds + c * TPITCH + 4 * q);
        *(float4*)(outb + (size_t)(c0 + c) * R + (r0 + 4 * q)) = v;
    }
}

// All three input transposes in one dispatch: z in [0, 3*NB)
__global__ __launch_bounds__(256) void transpose3_k(const float* __restrict__ Q,
                                                    const float* __restrict__ K,
                                                    const float* __restrict__ V,
                                                    float* __restrict__ Qt,
                                                    float* __restrict__ Kt,
                                                    float* __restrict__ Vt) {
    const int which = blockIdx.z / NB;
    const int b = blockIdx.z % NB;
    const size_t bo = (size_t)b * SEQ * ND;
    const float* in = (which == 0) ? Q : (which == 1) ? K : V;
    float* out = (which == 0) ? Qt : (which == 1) ? Kt : Vt;
    transpose64_body(in + bo, out + bo, SEQ, ND);  // [S,D] -> [D,S]
}

__global__ __launch_bounds__(256) void transpose_back_k(const float* __restrict__ in,
                                                        float* __restrict__ out) {
    const size_t bo = (size_t)blockIdx.z * SEQ * ND;
    transpose64_body(in + bo, out + bo, ND, SEQ);  // [D,S] -> [S,D]
}

// One workgroup per (b,d) lane: FFT cross-correlation -> top-8 -> time-delay agg.
// Qt/Kt/Vt are [B*D, SEQ]. Ot may alias Qt (each WG reads its Qt row before
// writing the same addresses as its Ot row).
// Data layout: zz[] holds (re,im) interleaved float2; tw2[] holds (cos,sin);
// tw2's memory is reused as the V staging buffer after the inverse FFT.
__global__ __launch_bounds__(256) void corr_topk_agg_k(const float* Qt,
                                                       const float* __restrict__ Kt,
                                                       const float* __restrict__ Vt,
                                                       float* Ot) {
    __shared__ float2 zz[SEQ + SEQ / 16];          // 4352 * 8B
    __shared__ float2 tw2[SEQ / 2 + SEQ / 32];     // 2176 * 8B (reused for V)
    __shared__ float sval[4];
    __shared__ int sidx[4];
    __shared__ float wsel[TOPK];
    __shared__ int dsel[TOPK];

    const int tid = threadIdx.x;
    const size_t row = (size_t)blockIdx.x * SEQ;

    // Twiddle table: tw[j] = exp(-2*pi*i*j/SEQ), j in [0, SEQ/2). Precise sincos.
    for (int j = tid; j < SEQ / 2; j += 256) {
        float s, c;
        sincosf(-6.283185307179586f * (float)j / (float)SEQ, &s, &c);
        tw2[PAD2(j)] = make_float2(c, s);
    }

    // Load z = Q + i*K (coalesced float4 from global; 4 consecutive points
    // never cross a PAD2 boundary, so zz writes are to consecutive slots).
    {
        const float4* Q4 = (const float4*)(Qt + row);
        const float4* K4 = (const float4*)(Kt + row);
        for (int t = tid; t < SEQ / 4; t += 256) {
            const float4 q = Q4[t];
            const float4 k = K4[t];
            const int b0 = PAD2(4 * t);
            zz[b0] = make_float2(q.x, k.x);
            zz[b0 + 1] = make_float2(q.y, k.y);
            zz[b0 + 2] = make_float2(q.z, k.z);
            zz[b0 + 3] = make_float2(q.w, k.w);
        }
    }
    __syncthreads();

    // Forward FFT: fused double radix-2 (radix-4 dataflow), DIF, exp(-),
    // natural input -> bit-reversed output.
    for (int h = 2048; h >= 2; h >>= 2) {
        const int hh = h >> 1;
        const int sA = SEQ / (2 * h);  // stage-A twiddle stride; stage-B = 2*sA
        for (int g = tid; g < SEQ / 4; g += 256) {
            const int pos = g & (hh - 1);
            const int i0 = ((g - pos) << 2) + pos;
            const int p0 = PAD2(i0), p1 = PAD2(i0 + hh);
            const int p2 = PAD2(i0 + h), p3 = PAD2(i0 + h + hh);
            const float2 e0 = zz[p0], e1 = zz[p1], e2 = zz[p2], e3 = zz[p3];
            const int ta = pos * sA;
            const float2 wA = tw2[PAD2(ta)];       // (c1, s1)
            const float2 wB = tw2[PAD2(2 * ta)];   // (cB, sB)
            // stage A (half = h): pairs (e0,e2) tw W^ta, (e1,e3) tw W^ta * (-i)
            const float f0r = e0.x + e2.x, f0i = e0.y + e2.y;
            float dr = e0.x - e2.x, di = e0.y - e2.y;
            const float f2r = dr * wA.x - di * wA.y, f2i = dr * wA.y + di * wA.x;
            const float f1r = e1.x + e3.x, f1i = e1.y + e3.y;
            dr = e1.x - e3.x;
            di = e1.y - e3.y;
            // (dr + i*di) * (s1 - i*c1):
            const float f3r = dr * wA.y + di * wA.x;
            const float f3i = di * wA.y - dr * wA.x;
            // stage B (half = hh): both pairs tw W^(2*ta)
            zz[p0] = make_float2(f0r + f1r, f0i + f1i);
            dr = f0r - f1r;
            di = f0i - f1i;
            zz[p1] = make_float2(dr * wB.x - di * wB.y, dr * wB.y + di * wB.x);
            zz[p2] = make_float2(f2r + f3r, f2i + f3i);
            dr = f2r - f3r;
            di = f2i - f3i;
            zz[p3] = make_float2(dr * wB.x - di * wB.y, dr * wB.y + di * wB.x);
        }
        __syncthreads();
    }

    // Cross spectrum P[f] = Qhat[f] * conj(Khat[f]) / SEQ, done in the
    // bit-reversed domain (register-staged; one read barrier, one write barrier).
    float2 za_[9], zb_[9];
#pragma unroll
    for (int q = 0; q < 9; ++q) {
        const int f = tid + (q << 8);
        if (f <= SEQ / 2) {
            za_[q] = zz[PAD2(rev12(f))];
            zb_[q] = zz[PAD2(rev12((SEQ - f) & (SEQ - 1)))];
        }
    }
    __syncthreads();
#pragma unroll
    for (int q = 0; q < 9; ++q) {
        const int f = tid + (q << 8);
        if (f <= SEQ / 2) {
            const float ar = za_[q].x, ai = za_[q].y;
            const float br = zb_[q].x, bi = zb_[q].y;
            const float Qr = 0.5f * (ar + br), Qi = 0.5f * (ai - bi);
            const float Kr = 0.5f * (ai + bi), Ki = 0.5f * (br - ar);
            const float invS = 1.0f / (float)SEQ;
            const float Pr = (Qr * Kr + Qi * Ki) * invS;
            const float Pi = (Qi * Kr - Qr * Ki) * invS;
            zz[PAD2(rev12(f))] = make_float2(Pr, Pi);
            zz[PAD2(rev12((SEQ - f) & (SEQ - 1)))] = make_float2(Pr, -Pi);
        }
    }
    __syncthreads();

    // Inverse FFT: fused double radix-2 DIT, exp(+), bit-reversed -> natural.
    // (1/SEQ already folded into P.)
    for (int hh = 1; hh <= 1024; hh <<= 2) {
        const int sA = SEQ / (2 * hh);  // stage-A twiddle stride
        const int sB = SEQ / (4 * hh);  // stage-B twiddle stride
        for (int g = tid; g < SEQ / 4; g += 256) {
            const int pos = g & (hh - 1);
            const int i0 = ((g - pos) << 2) + pos;
            const int p0 = PAD2(i0), p1 = PAD2(i0 + hh);
            const int p2 = PAD2(i0 + 2 * hh), p3 = PAD2(i0 + 3 * hh);
            const float2 e0 = zz[p0], e1 = zz[p1], e2 = zz[p2], e3 = zz[p3];
            const float2 wA = tw2[PAD2(pos * sA)];
            const float2 wB = tw2[PAD2(pos * sB)];
            const float cA = wA.x, sAv = -wA.y;
            const float cB = wB.x, sBv = -wB.y;
            // stage A (half = hh): both pairs tw conj(W^ta)
            float tr = e1.x * cA - e1.y * sAv, ti = e1.x * sAv + e1.y * cA;
            const float f0r = e0.x + tr, f0i = e0.y + ti;
            const float f1r = e0.x - tr, f1i = e0.y - ti;
            tr = e3.x * cA - e3.y * sAv;
            ti = e3.x * sAv + e3.y * cA;
            const float f2r = e2.x + tr, f2i = e2.y + ti;
            const float f3r = e2.x - tr, f3i = e2.y - ti;
            // stage B (half = 2*hh): pair (f0,f2) tw conj(W^tb);
            // pair (f1,f3) tw conj(W^(tb + SEQ/4)) = conj(W^tb) * i = (-sBv, cB)
            tr = f2r * cB - f2i * sBv;
            ti = f2r * sBv + f2i * cB;
            zz[p0] = make_float2(f0r + tr, f0i + ti);
            zz[p2] = make_float2(f0r - tr, f0i - ti);
            tr = -f3r * sBv - f3i * cB;
            ti = f3r * cB - f3i * sBv;
            zz[p1] = make_float2(f1r + tr, f1i + ti);
            zz[p3] = make_float2(f1r - tr, f1i - ti);
        }
        __syncthreads();
    }
    // zz[t].x now holds corr[t] (imaginary residue discarded). Twiddles dead.

    // Stage V row into tw2's memory viewed as floats (PADF layout).
    // Visibility to the aggregation phase is guaranteed by the top-k barriers.
    float* vbuf = reinterpret_cast<float*>(tw2);
    {
        const float4* V4 = (const float4*)(Vt + row);
        for (int t = tid; t < SEQ / 4; t += 256) {
            const float4 v = V4[t];
            const int b0 = PADF(4 * t);
            vbuf[b0] = v.x; vbuf[b0 + 1] = v.y;
            vbuf[b0 + 2] = v.z; vbuf[b0 + 3] = v.w;
        }
    }

    // Top-8 selection (argmax x8; ties -> lower index, matching jax.lax.top_k).
    // Candidates cached in registers; winner poisoned in-register via the
    // broadcast dsel[it] with compile-time-unrolled indexing (no scratch).
    float vals[16];
#pragma unroll
    for (int j = 0; j < 16; ++j) {
        vals[j] = zz[PAD2(tid + (j << 8))].x;
    }
    for (int it = 0; it < TOPK; ++it) {
        float best = NEGINF;
        int bidx = 0;
#pragma unroll
        for (int j = 0; j < 16; ++j) {
            const int t = tid + (j << 8);
            if (vals[j] > best) {  // strict: keeps lowest index on ties
                best = vals[j];
                bidx = t;
            }
        }
#pragma unroll
        for (int off = 32; off > 0; off >>= 1) {
            const float ov = __shfl_down(best, off);
            const int oi = __shfl_down(bidx, off);
            if (ov > best || (ov == best && oi < bidx)) {
                best = ov;
                bidx = oi;
            }
        }
        if ((tid & 63) == 0) {
            sval[tid >> 6] = best;
            sidx[tid >> 6] = bidx;
        }
        __syncthreads();
        if (tid == 0) {
            float bv = sval[0];
            int bi2 = sidx[0];
#pragma unroll
            for (int w = 1; w < 4; ++w) {
                const float ov = sval[w];
                const int oi = sidx[w];
                if (ov > bv || (ov == bv && oi < bi2)) {
                    bv = ov;
                    bi2 = oi;
                }
            }
            wsel[it] = bv;
            dsel[it] = bi2;
        }
        __syncthreads();
        const int win = dsel[it];
#pragma unroll
        for (int j = 0; j < 16; ++j) {
            if (tid + (j << 8) == win) vals[j] = NEGINF;
        }
    }

    // Aggregation: out[t] = sum_k w_k * V[(t + delay_k) & (SEQ-1)].
    float w[TOPK];
    int dl[TOPK];
#pragma unroll
    for (int k = 0; k < TOPK; ++k) {
        w[k] = wsel[k];
        dl[k] = dsel[k];
    }
    for (int j = 0; j < SEQ / 256; ++j) {
        const int t = tid + (j << 8);
        float acc = 0.0f;
#pragma unroll
        for (int k = 0; k < TOPK; ++k) {
            acc += w[k] * vbuf[PADF((t + dl[k]) & (SEQ - 1))];
        }
        Ot[row + t] = acc;
    }
}

extern "C" void kernel_launch(void* const* d_in, const int* in_sizes, int n_in,
                              void* d_out, int out_size, void* d_ws, size_t ws_size,
                              hipStream_t stream) {
    const float* Q = (const float*)d_in[0];
    const float* K = (const float*)d_in[1];
    const float* V = (const float*)d_in[2];
    float* out = (float*)d_out;

    const size_t n = (size_t)NB * ND * SEQ;  // 8388608 elements per tensor
    float* Qt = (float*)d_ws;  // [B*D, S]; also reused as Ot (safe aliasing)
    float* Kt = Qt + n;
    float* Vt = Kt + n;

    // [B,S,D] -> [B,D,S] for Q, K, V in one dispatch (64x64 float4 tiles).
    dim3 g1(ND / 64, SEQ / 64, 3 * NB);
    hipLaunchKernelGGL(transpose3_k, g1, dim3(256), 0, stream, Q, K, V, Qt, Kt, Vt);

    // Per-lane FFT correlation + top-k + aggregation. Ot aliases Qt.
    hipLaunchKernelGGL(corr_topk_agg_k, dim3(NB * ND), dim3(256), 0, stream,
                       Qt, Kt, Vt, Qt);

    // [B,D,S] -> [B,S,D]
    dim3 g3(SEQ / 64, ND / 64, NB);
    hipLaunchKernelGGL(transpose_back_k, g3, dim3(256), 0, stream, Qt, out);
}

// Round 7
// 242.282 us; speedup vs baseline: 1.0969x; 1.0969x over previous
//
#include <hip/hip_runtime.h>
#include <math.h>

#define SEQ 4096
#define LOG2SEQ 12
#define TOPK 8
#define NB 16
#define ND 128
#define NEGINF (-3.402823466e+38f)

// LDS anti-bank-conflict padding: insert one float per 32.
#define PADF(i) ((i) + ((i) >> 5))

// LDS pitch (floats) for the 64x64 transpose tile: 68*4=272B, 16B-aligned so
// float4 LDS reads are legal; +4 pad rotates banks across rows.
#define TPITCH 68

__device__ __forceinline__ int rev12(int x) {
    return (int)(__brev((unsigned)x) >> (32 - LOG2SEQ));
}

// Twiddle: c = cos(-2*pi*idx/SEQ), s = sin(-2*pi*idx/SEQ), via hw v_sin/v_cos.
// Matches the old table convention (twc[j], tws[j]); double-angle identities
// on (c,s) stay sign-consistent: c2 = c*c - s*s, s2 = 2*s*c.
__device__ __forceinline__ void twid(int idx, float& c, float& s) {
    const float a = (float)idx * (-0.001533980787885641f);  // -2*pi/4096
    c = __cosf(a);
    s = __sinf(a);
}

// 64x64 tiled transpose body: in is [R][C], out is [C][R]; both multiples of 64.
// float4 on both global sides; LDS staged as lds[col*TPITCH + row].
__device__ __forceinline__ void transpose64_body(const float* __restrict__ inb,
                                                 float* __restrict__ outb,
                                                 int R, int C) {
    __shared__ float lds[64 * TPITCH];
    const int tid = threadIdx.x;
    const int c0 = blockIdx.x * 64, r0 = blockIdx.y * 64;
    const int q = tid & 15;          // float4 index within 64-wide span
    const int rr = tid >> 4;         // 16 rows per pass
#pragma unroll
    for (int pass = 0; pass < 4; ++pass) {
        const int r = pass * 16 + rr;
        const float4 v =
            *(const float4*)(inb + (size_t)(r0 + r) * C + (c0 + 4 * q));
        const int base = (4 * q) * TPITCH + r;  // scatter: transposed in LDS
        lds[base] = v.x;
        lds[base + TPITCH] = v.y;
        lds[base + 2 * TPITCH] = v.z;
        lds[base + 3 * TPITCH] = v.w;
    }
    __syncthreads();
#pragma unroll
    for (int pass = 0; pass < 4; ++pass) {
        const int c = pass * 16 + rr;  // local output row (= input col)
        const float4 v = *(const float4*)(lds + c * TPITCH + 4 * q);
        *(float4*)(outb + (size_t)(c0 + c) * R + (r0 + 4 * q)) = v;
    }
}

// All three input transposes in one dispatch: z in [0, 3*NB)
__global__ __launch_bounds__(256) void transpose3_k(const float* __restrict__ Q,
                                                    const float* __restrict__ K,
                                                    const float* __restrict__ V,
                                                    float* __restrict__ Qt,
                                                    float* __restrict__ Kt,
                                                    float* __restrict__ Vt) {
    const int which = blockIdx.z / NB;
    const int b = blockIdx.z % NB;
    const size_t bo = (size_t)b * SEQ * ND;
    const float* in = (which == 0) ? Q : (which == 1) ? K : V;
    float* out = (which == 0) ? Qt : (which == 1) ? Kt : Vt;
    transpose64_body(in + bo, out + bo, SEQ, ND);  // [S,D] -> [D,S]
}

__global__ __launch_bounds__(256) void transpose_back_k(const float* __restrict__ in,
                                                        float* __restrict__ out) {
    const size_t bo = (size_t)blockIdx.z * SEQ * ND;
    transpose64_body(in + bo, out + bo, ND, SEQ);  // [D,S] -> [S,D]
}

// One workgroup per (b,d) lane: FFT cross-correlation -> top-8 -> time-delay agg.
// Qt/Kt/Vt are [B*D, SEQ]. Ot may alias Qt (each WG reads its Qt row before
// writing the same addresses as its Ot row).
// LDS: re/im only (~34 KB) -> 4 WG/CU. Twiddles computed in registers.
__global__ __launch_bounds__(256) void corr_topk_agg_k(const float* Qt,
                                                       const float* __restrict__ Kt,
                                                       const float* __restrict__ Vt,
                                                       float* Ot) {
    __shared__ float re[SEQ + SEQ / 32];
    __shared__ float im[SEQ + SEQ / 32];
    __shared__ float sval[4];
    __shared__ int sidx[4];
    __shared__ float wsel[TOPK];
    __shared__ int dsel[TOPK];

    const int tid = threadIdx.x;
    const size_t row = (size_t)blockIdx.x * SEQ;

    // Load z = Q + i*K (coalesced float4 from global; scalar LDS writes since
    // padding breaks 16B contiguity at 32-float boundaries).
    {
        const float4* Q4 = (const float4*)(Qt + row);
        const float4* K4 = (const float4*)(Kt + row);
        for (int t = tid; t < SEQ / 4; t += 256) {
            const float4 q = Q4[t];
            const float4 k = K4[t];
            const int b0 = PADF(4 * t);  // 4t..4t+3 never cross a pad boundary
            re[b0] = q.x; re[b0 + 1] = q.y; re[b0 + 2] = q.z; re[b0 + 3] = q.w;
            im[b0] = k.x; im[b0 + 1] = k.y; im[b0 + 2] = k.z; im[b0 + 3] = k.w;
        }
    }
    __syncthreads();

    // Forward FFT: fused double radix-2 (radix-4 dataflow), DIF, exp(-),
    // natural input -> bit-reversed output. Stage-A twiddle W^ta computed via
    // hw sincos; stage-B twiddle W^(2ta) via double-angle.
    for (int h = 2048; h >= 2; h >>= 2) {
        const int hh = h >> 1;
        const int sA = SEQ / (2 * h);  // stage-A twiddle stride
        for (int g = tid; g < SEQ / 4; g += 256) {
            const int pos = g & (hh - 1);
            const int i0 = ((g - pos) << 2) + pos;
            const int p0 = PADF(i0), p1 = PADF(i0 + hh);
            const int p2 = PADF(i0 + h), p3 = PADF(i0 + h + hh);
            const float e0r = re[p0], e0i = im[p0];
            const float e1r = re[p1], e1i = im[p1];
            const float e2r = re[p2], e2i = im[p2];
            const float e3r = re[p3], e3i = im[p3];
            float c1, s1;
            twid(pos * sA, c1, s1);
            const float cB = c1 * c1 - s1 * s1;
            const float sB = 2.0f * s1 * c1;
            // stage A (half = h): pairs (e0,e2) tw W^ta, (e1,e3) tw W^ta * (-i)
            const float f0r = e0r + e2r, f0i = e0i + e2i;
            float dr = e0r - e2r, di = e0i - e2i;
            const float f2r = dr * c1 - di * s1, f2i = dr * s1 + di * c1;
            const float f1r = e1r + e3r, f1i = e1i + e3i;
            dr = e1r - e3r;
            di = e1i - e3i;
            // (dr + i*di) * (s1 - i*c1):
            const float f3r = dr * s1 + di * c1;
            const float f3i = di * s1 - dr * c1;
            // stage B (half = hh): both pairs tw W^(2*ta)
            re[p0] = f0r + f1r;
            im[p0] = f0i + f1i;
            dr = f0r - f1r;
            di = f0i - f1i;
            re[p1] = dr * cB - di * sB;
            im[p1] = dr * sB + di * cB;
            re[p2] = f2r + f3r;
            im[p2] = f2i + f3i;
            dr = f2r - f3r;
            di = f2i - f3i;
            re[p3] = dr * cB - di * sB;
            im[p3] = dr * sB + di * cB;
        }
        __syncthreads();
    }

    // Cross spectrum P[f] = Qhat[f] * conj(Khat[f]) / SEQ, done in the
    // bit-reversed domain (register-staged; one read barrier, one write barrier).
    float ar_[9], ai_[9], br_[9], bi_[9];
#pragma unroll
    for (int q = 0; q < 9; ++q) {
        const int f = tid + (q << 8);
        if (f <= SEQ / 2) {
            const int pa = PADF(rev12(f));
            const int pb = PADF(rev12((SEQ - f) & (SEQ - 1)));
            ar_[q] = re[pa];
            ai_[q] = im[pa];
            br_[q] = re[pb];
            bi_[q] = im[pb];
        }
    }
    __syncthreads();
#pragma unroll
    for (int q = 0; q < 9; ++q) {
        const int f = tid + (q << 8);
        if (f <= SEQ / 2) {
            const float ar = ar_[q], ai = ai_[q], br = br_[q], bi = bi_[q];
            const float Qr = 0.5f * (ar + br), Qi = 0.5f * (ai - bi);
            const float Kr = 0.5f * (ai + bi), Ki = 0.5f * (br - ar);
            const float invS = 1.0f / (float)SEQ;
            const float Pr = (Qr * Kr + Qi * Ki) * invS;
            const float Pi = (Qi * Kr - Qr * Ki) * invS;
            const int pa = PADF(rev12(f));
            const int pb = PADF(rev12((SEQ - f) & (SEQ - 1)));
            re[pa] = Pr;
            im[pa] = Pi;
            re[pb] = Pr;
            im[pb] = -Pi;
        }
    }
    __syncthreads();

    // Inverse FFT: fused double radix-2 DIT, exp(+), bit-reversed -> natural.
    // (1/SEQ already folded into P.) Stage-B twiddle (smaller angle) via hw
    // sincos; stage-A twiddle (2x angle) via double-angle.
    for (int hh = 1; hh <= 1024; hh <<= 2) {
        const int sB = SEQ / (4 * hh);  // stage-B twiddle stride (sA = 2*sB)
        for (int g = tid; g < SEQ / 4; g += 256) {
            const int pos = g & (hh - 1);
            const int i0 = ((g - pos) << 2) + pos;
            const int p0 = PADF(i0), p1 = PADF(i0 + hh);
            const int p2 = PADF(i0 + 2 * hh), p3 = PADF(i0 + 3 * hh);
            const float e0r = re[p0], e0i = im[p0];
            const float e1r = re[p1], e1i = im[p1];
            const float e2r = re[p2], e2i = im[p2];
            const float e3r = re[p3], e3i = im[p3];
            float cB0, sB0;
            twid(pos * sB, cB0, sB0);
            const float cA = cB0 * cB0 - sB0 * sB0;   // twc at 2x index
            const float sAv = -2.0f * sB0 * cB0;      // -(tws at 2x index)
            const float cB = cB0;
            const float sBv = -sB0;                   // -(tws at index)
            // stage A (half = hh): both pairs tw conj(W^ta)
            float tr = e1r * cA - e1i * sAv, ti = e1r * sAv + e1i * cA;
            const float f0r = e0r + tr, f0i = e0i + ti;
            const float f1r = e0r - tr, f1i = e0i - ti;
            tr = e3r * cA - e3i * sAv;
            ti = e3r * sAv + e3i * cA;
            const float f2r = e2r + tr, f2i = e2i + ti;
            const float f3r = e2r - tr, f3i = e2i - ti;
            // stage B (half = 2*hh): pair (f0,f2) tw conj(W^tb);
            // pair (f1,f3) tw conj(W^(tb + SEQ/4)) = conj(W^tb) * i = (-sBv, cB)
            tr = f2r * cB - f2i * sBv;
            ti = f2r * sBv + f2i * cB;
            re[p0] = f0r + tr;
            im[p0] = f0i + ti;
            re[p2] = f0r - tr;
            im[p2] = f0i - ti;
            tr = -f3r * sBv - f3i * cB;
            ti = f3r * cB - f3i * sBv;
            re[p1] = f1r + tr;
            im[p1] = f1i + ti;
            re[p3] = f1r - tr;
            im[p3] = f1i - ti;
        }
        __syncthreads();
    }
    // re[t] now holds corr[t] (imaginary residue discarded).

    // Stage V row into im[] (free after inverse FFT). Visibility to the
    // aggregation phase is guaranteed by the top-k barriers below.
    {
        const float4* V4 = (const float4*)(Vt + row);
        for (int t = tid; t < SEQ / 4; t += 256) {
            const float4 v = V4[t];
            const int b0 = PADF(4 * t);
            im[b0] = v.x; im[b0 + 1] = v.y; im[b0 + 2] = v.z; im[b0 + 3] = v.w;
        }
    }

    // Top-8 selection (argmax x8; ties -> lower index, matching jax.lax.top_k).
    // Candidates cached in registers; winner poisoned in-register via the
    // broadcast dsel[it] with compile-time-unrolled indexing (no scratch).
    float vals[16];
#pragma unroll
    for (int j = 0; j < 16; ++j) {
        vals[j] = re[PADF(tid + (j << 8))];
    }
    for (int it = 0; it < TOPK; ++it) {
        float best = NEGINF;
        int bidx = 0;
#pragma unroll
        for (int j = 0; j < 16; ++j) {
            const int t = tid + (j << 8);
            if (vals[j] > best) {  // strict: keeps lowest index on ties
                best = vals[j];
                bidx = t;
            }
        }
#pragma unroll
        for (int off = 32; off > 0; off >>= 1) {
            const float ov = __shfl_down(best, off);
            const int oi = __shfl_down(bidx, off);
            if (ov > best || (ov == best && oi < bidx)) {
                best = ov;
                bidx = oi;
            }
        }
        if ((tid & 63) == 0) {
            sval[tid >> 6] = best;
            sidx[tid >> 6] = bidx;
        }
        __syncthreads();
        if (tid == 0) {
            float bv = sval[0];
            int bi2 = sidx[0];
#pragma unroll
            for (int w = 1; w < 4; ++w) {
                const float ov = sval[w];
                const int oi = sidx[w];
                if (ov > bv || (ov == bv && oi < bi2)) {
                    bv = ov;
                    bi2 = oi;
                }
            }
            wsel[it] = bv;
            dsel[it] = bi2;
        }
        __syncthreads();
        const int win = dsel[it];
#pragma unroll
        for (int j = 0; j < 16; ++j) {
            if (tid + (j << 8) == win) vals[j] = NEGINF;
        }
    }

    // Aggregation: out[t] = sum_k w_k * V[(t + delay_k) & (SEQ-1)].
    float w[TOPK];
    int dl[TOPK];
#pragma unroll
    for (int k = 0; k < TOPK; ++k) {
        w[k] = wsel[k];
        dl[k] = dsel[k];
    }
    for (int j = 0; j < SEQ / 256; ++j) {
        const int t = tid + (j << 8);
        float acc = 0.0f;
#pragma unroll
        for (int k = 0; k < TOPK; ++k) {
            acc += w[k] * im[PADF((t + dl[k]) & (SEQ - 1))];
        }
        Ot[row + t] = acc;
    }
}

extern "C" void kernel_launch(void* const* d_in, const int* in_sizes, int n_in,
                              void* d_out, int out_size, void* d_ws, size_t ws_size,
                              hipStream_t stream) {
    const float* Q = (const float*)d_in[0];
    const float* K = (const float*)d_in[1];
    const float* V = (const float*)d_in[2];
    float* out = (float*)d_out;

    const size_t n = (size_t)NB * ND * SEQ;  // 8388608 elements per tensor
    float* Qt = (float*)d_ws;  // [B*D, S]; also reused as Ot (safe aliasing)
    float* Kt = Qt + n;
    float* Vt = Kt + n;

    // [B,S,D] -> [B,D,S] for Q, K, V in one dispatch (64x64 float4 tiles).
    dim3 g1(ND / 64, SEQ / 64, 3 * NB);
    hipLaunchKernelGGL(transpose3_k, g1, dim3(256), 0, stream, Q, K, V, Qt, Kt, Vt);

    // Per-lane FFT correlation + top-k + aggregation. Ot aliases Qt.
    hipLaunchKernelGGL(corr_topk_agg_k, dim3(NB * ND), dim3(256), 0, stream,
                       Qt, Kt, Vt, Qt);

    // [B,D,S] -> [B,S,D]
    dim3 g3(SEQ / 64, ND / 64, NB);
    hipLaunchKernelGGL(transpose_back_k, g3, dim3(256), 0, stream, Qt, out);
}

// Round 12
// 231.953 us; speedup vs baseline: 1.1457x; 1.0445x over previous
//
#include <hip/hip_runtime.h>
#include <math.h>

#define SEQ 4096
#define LOG2SEQ 12
#define TOPK 8
#define NB 16
#define ND 128
#define NEGINF (-3.402823466e+38f)
#define RSQ2 0.70710678118654752f

// LDS anti-bank-conflict padding: insert one float per 32.
#define PADF(i) ((i) + ((i) >> 5))

// LDS pitch (floats) for the 64x64 transpose tile: 68*4=272B, 16B-aligned so
// float4 LDS reads are legal; +4 pad rotates banks across rows.
#define TPITCH 68

__device__ __forceinline__ int rev12(int x) {
    return (int)(__brev((unsigned)x) >> (32 - LOG2SEQ));
}

// Twiddle: c = cos(-2*pi*idx/SEQ), s = sin(-2*pi*idx/SEQ), via hw v_sin/v_cos.
// Double-angle identities on (c,s) stay sign-consistent: c2=c*c-s*s, s2=2*s*c.
__device__ __forceinline__ void twid(int idx, float& c, float& s) {
    const float a = (float)idx * (-0.001533980787885641f);  // -2*pi/4096
    c = __cosf(a);
    s = __sinf(a);
}

// t = x * (wr + i*wi)
#define CMUL(tr, ti, xr, xi, wr, wi) \
    { tr = (xr) * (wr) - (xi) * (wi); ti = (xr) * (wi) + (xi) * (wr); }
// t = x * conj(wr + i*wi)
#define CMULC(tr, ti, xr, xi, wr, wi) \
    { tr = (xr) * (wr) + (xi) * (wi); ti = (xi) * (wr) - (xr) * (wi); }

// 64x64 tiled transpose body: in is [R][C], out is [C][R]; both multiples of 64.
// float4 on both global sides; LDS staged as lds[col*TPITCH + row].
__device__ __forceinline__ void transpose64_body(const float* __restrict__ inb,
                                                 float* __restrict__ outb,
                                                 int R, int C) {
    __shared__ float lds[64 * TPITCH];
    const int tid = threadIdx.x;
    const int c0 = blockIdx.x * 64, r0 = blockIdx.y * 64;
    const int q = tid & 15;          // float4 index within 64-wide span
    const int rr = tid >> 4;         // 16 rows per pass
#pragma unroll
    for (int pass = 0; pass < 4; ++pass) {
        const int r = pass * 16 + rr;
        const float4 v =
            *(const float4*)(inb + (size_t)(r0 + r) * C + (c0 + 4 * q));
        const int base = (4 * q) * TPITCH + r;  // scatter: transposed in LDS
        lds[base] = v.x;
        lds[base + TPITCH] = v.y;
        lds[base + 2 * TPITCH] = v.z;
        lds[base + 3 * TPITCH] = v.w;
    }
    __syncthreads();
#pragma unroll
    for (int pass = 0; pass < 4; ++pass) {
        const int c = pass * 16 + rr;  // local output row (= input col)
        const float4 v = *(const float4*)(lds + c * TPITCH + 4 * q);
        *(float4*)(outb + (size_t)(c0 + c) * R + (r0 + 4 * q)) = v;
    }
}

// All three input transposes in one dispatch: z in [0, 3*NB)
__global__ __launch_bounds__(256) void transpose3_k(const float* __restrict__ Q,
                                                    const float* __restrict__ K,
                                                    const float* __restrict__ V,
                                                    float* __restrict__ Qt,
                                                    float* __restrict__ Kt,
                                                    float* __restrict__ Vt) {
    const int which = blockIdx.z / NB;
    const int b = blockIdx.z % NB;
    const size_t bo = (size_t)b * SEQ * ND;
    const float* in = (which == 0) ? Q : (which == 1) ? K : V;
    float* out = (which == 0) ? Qt : (which == 1) ? Kt : Vt;
    transpose64_body(in + bo, out + bo, SEQ, ND);  // [S,D] -> [D,S]
}

__global__ __launch_bounds__(256) void transpose_back_k(const float* __restrict__ in,
                                                        float* __restrict__ out) {
    const size_t bo = (size_t)blockIdx.z * SEQ * ND;
    transpose64_body(in + bo, out + bo, ND, SEQ);  // [D,S] -> [S,D]
}

// One workgroup per (b,d) lane: FFT cross-correlation -> top-8 -> time-delay agg.
// Qt/Kt/Vt are [B*D, SEQ]. Ot may alias Qt (each WG reads its Qt row before
// writing the same addresses as its Ot row).
// Radix-8 dataflow (3 fused radix-2 stages per LDS pass): 4 fwd + 4 inv passes.
// Verified as a strict regrouping of the radix-2 DIF/DIT cascade, so the
// bit-reversed spectrum indexing (rev12) is unchanged.
__global__ __launch_bounds__(256) void corr_topk_agg_k(const float* Qt,
                                                       const float* __restrict__ Kt,
                                                       const float* __restrict__ Vt,
                                                       float* Ot) {
    __shared__ float re[SEQ + SEQ / 32];
    __shared__ float im[SEQ + SEQ / 32];
    __shared__ float sval[4];
    __shared__ int sidx[4];
    __shared__ float wsel[TOPK];
    __shared__ int dsel[TOPK];

    const int tid = threadIdx.x;
    const size_t row = (size_t)blockIdx.x * SEQ;

    // Load z = Q + i*K (coalesced float4 from global; scalar LDS writes since
    // padding breaks 16B contiguity at 32-float boundaries).
    {
        const float4* Q4 = (const float4*)(Qt + row);
        const float4* K4 = (const float4*)(Kt + row);
        for (int t = tid; t < SEQ / 4; t += 256) {
            const float4 q = Q4[t];
            const float4 k = K4[t];
            const int b0 = PADF(4 * t);  // 4t..4t+3 never cross a pad boundary
            re[b0] = q.x; re[b0 + 1] = q.y; re[b0 + 2] = q.z; re[b0 + 3] = q.w;
            im[b0] = k.x; im[b0 + 1] = k.y; im[b0 + 2] = k.z; im[b0 + 3] = k.w;
        }
    }
    __syncthreads();

    // Forward FFT: fused triple radix-2 (radix-8 dataflow), DIF, exp(-),
    // natural input -> bit-reversed output. Stage halves per pass: (4hq,2hq,hq).
    for (int h = 2048; h >= 4; h >>= 3) {
        const int hq = h >> 2;
        const int sA = SEQ / (8 * hq);  // stage-A twiddle stride
        for (int g = tid; g < SEQ / 8; g += 256) {
            const int pos = g & (hq - 1);
            const int i0 = ((g - pos) << 3) + pos;
            int p[8];
#pragma unroll
            for (int j = 0; j < 8; ++j) p[j] = PADF(i0 + j * hq);
            float er[8], ei[8];
#pragma unroll
            for (int j = 0; j < 8; ++j) { er[j] = re[p[j]]; ei[j] = im[p[j]]; }
            float c1, s1;
            twid(pos * sA, c1, s1);
            const float c2 = c1 * c1 - s1 * s1, s2 = 2.0f * s1 * c1;
            const float c4 = c2 * c2 - s2 * s2, s4 = 2.0f * s2 * c2;
            const float t1r = RSQ2 * (c1 + s1), t1i = RSQ2 * (s1 - c1);
            // Stage A (half=4hq): pairs (j, j+4), tw W^ta * w8^j
            float ar[8], ai[8];
#pragma unroll
            for (int j = 0; j < 4; ++j) {
                ar[j] = er[j] + er[j + 4];
                ai[j] = ei[j] + ei[j + 4];
            }
            float dr, di;
            dr = er[0] - er[4]; di = ei[0] - ei[4];
            CMUL(ar[4], ai[4], dr, di, c1, s1);
            dr = er[1] - er[5]; di = ei[1] - ei[5];
            CMUL(ar[5], ai[5], dr, di, t1r, t1i);
            dr = er[2] - er[6]; di = ei[2] - ei[6];
            CMUL(ar[6], ai[6], dr, di, s1, -c1);
            dr = er[3] - er[7]; di = ei[3] - ei[7];
            CMUL(ar[7], ai[7], dr, di, t1i, -t1r);
            // Stage B (half=2hq): pairs (0,2),(4,6) tw W^2ta; (1,3),(5,7) tw W^2ta*(-i)
            float br[8], bi[8];
#pragma unroll
            for (int base = 0; base < 8; base += 4) {
                br[base] = ar[base] + ar[base + 2];
                bi[base] = ai[base] + ai[base + 2];
                dr = ar[base] - ar[base + 2]; di = ai[base] - ai[base + 2];
                CMUL(br[base + 2], bi[base + 2], dr, di, c2, s2);
                br[base + 1] = ar[base + 1] + ar[base + 3];
                bi[base + 1] = ai[base + 1] + ai[base + 3];
                dr = ar[base + 1] - ar[base + 3]; di = ai[base + 1] - ai[base + 3];
                CMUL(br[base + 3], bi[base + 3], dr, di, s2, -c2);
            }
            // Stage C (half=hq): pairs (j, j+1), all tw W^4ta
#pragma unroll
            for (int j = 0; j < 8; j += 2) {
                const float sr = br[j] + br[j + 1], si = bi[j] + bi[j + 1];
                dr = br[j] - br[j + 1]; di = bi[j] - bi[j + 1];
                float or_, oi_;
                CMUL(or_, oi_, dr, di, c4, s4);
                re[p[j]] = sr; im[p[j]] = si;
                re[p[j + 1]] = or_; im[p[j + 1]] = oi_;
            }
        }
        __syncthreads();
    }

    // Cross spectrum P[f] = Qhat[f] * conj(Khat[f]) / SEQ, done in the
    // bit-reversed domain (register-staged; one read barrier, one write barrier).
    float ar_[9], ai_[9], br_[9], bi_[9];
#pragma unroll
    for (int q = 0; q < 9; ++q) {
        const int f = tid + (q << 8);
        if (f <= SEQ / 2) {
            const int pa = PADF(rev12(f));
            const int pb = PADF(rev12((SEQ - f) & (SEQ - 1)));
            ar_[q] = re[pa];
            ai_[q] = im[pa];
            br_[q] = re[pb];
            bi_[q] = im[pb];
        }
    }
    __syncthreads();
#pragma unroll
    for (int q = 0; q < 9; ++q) {
        const int f = tid + (q << 8);
        if (f <= SEQ / 2) {
            const float ar = ar_[q], ai = ai_[q], br = br_[q], bi = bi_[q];
            const float Qr = 0.5f * (ar + br), Qi = 0.5f * (ai - bi);
            const float Kr = 0.5f * (ai + bi), Ki = 0.5f * (br - ar);
            const float invS = 1.0f / (float)SEQ;
            const float Pr = (Qr * Kr + Qi * Ki) * invS;
            const float Pi = (Qi * Kr - Qr * Ki) * invS;
            const int pa = PADF(rev12(f));
            const int pb = PADF(rev12((SEQ - f) & (SEQ - 1)));
            re[pa] = Pr;
            im[pa] = Pi;
            re[pb] = Pr;
            im[pb] = -Pi;
        }
    }
    __syncthreads();

    // Inverse FFT: fused triple radix-2 DIT, exp(+), bit-reversed -> natural.
    // (1/SEQ folded into P.) Stage halves per pass: (hq, 2hq, 4hq).
    for (int hq = 1; hq <= 512; hq <<= 3) {
        const int sA = SEQ / (8 * hq);
        for (int g = tid; g < SEQ / 8; g += 256) {
            const int pos = g & (hq - 1);
            const int i0 = ((g - pos) << 3) + pos;
            int p[8];
#pragma unroll
            for (int j = 0; j < 8; ++j) p[j] = PADF(i0 + j * hq);
            float er[8], ei[8];
#pragma unroll
            for (int j = 0; j < 8; ++j) { er[j] = re[p[j]]; ei[j] = im[p[j]]; }
            float c1, s1;
            twid(pos * sA, c1, s1);
            const float c2 = c1 * c1 - s1 * s1, s2 = 2.0f * s1 * c1;
            const float c4 = c2 * c2 - s2 * s2, s4 = 2.0f * s2 * c2;
            const float u1r = RSQ2 * (c1 + s1), u1i = RSQ2 * (c1 - s1);
            float tr, ti;
            // Stage A (half=hq): pairs (j, j+1), tw conj(W^4ta)
            float ar[8], ai[8];
#pragma unroll
            for (int j = 0; j < 8; j += 2) {
                CMULC(tr, ti, er[j + 1], ei[j + 1], c4, s4);
                ar[j] = er[j] + tr; ai[j] = ei[j] + ti;
                ar[j + 1] = er[j] - tr; ai[j + 1] = ei[j] - ti;
            }
            // Stage B (half=2hq): (0,2),(4,6) tw conj(W^2ta); (1,3),(5,7) tw conj(W^2ta)*i
            float br[8], bi[8];
#pragma unroll
            for (int base = 0; base < 8; base += 4) {
                CMULC(tr, ti, ar[base + 2], ai[base + 2], c2, s2);
                br[base] = ar[base] + tr; bi[base] = ai[base] + ti;
                br[base + 2] = ar[base] - tr; bi[base + 2] = ai[base] - ti;
                CMUL(tr, ti, ar[base + 3], ai[base + 3], s2, c2);
                br[base + 1] = ar[base + 1] + tr; bi[base + 1] = ai[base + 1] + ti;
                br[base + 3] = ar[base + 1] - tr; bi[base + 3] = ai[base + 1] - ti;
            }
            // Stage C (half=4hq): pairs (j, j+4), tw conj(W^ta) * conj(w8^j)
            CMULC(tr, ti, br[4], bi[4], c1, s1);
            re[p[0]] = br[0] + tr; im[p[0]] = bi[0] + ti;
            re[p[4]] = br[0] - tr; im[p[4]] = bi[0] - ti;
            CMUL(tr, ti, br[5], bi[5], u1r, u1i);
            re[p[1]] = br[1] + tr; im[p[1]] = bi[1] + ti;
            re[p[5]] = br[1] - tr; im[p[5]] = bi[1] - ti;
            CMUL(tr, ti, br[6], bi[6], s1, c1);
            re[p[2]] = br[2] + tr; im[p[2]] = bi[2] + ti;
            re[p[6]] = br[2] - tr; im[p[6]] = bi[2] - ti;
            CMUL(tr, ti, br[7], bi[7], -u1i, u1r);
            re[p[3]] = br[3] + tr; im[p[3]] = bi[3] + ti;
            re[p[7]] = br[3] - tr; im[p[7]] = bi[3] - ti;
        }
        __syncthreads();
    }
    // re[t] now holds corr[t] (imaginary residue discarded).

    // Stage V row into im[] (free after inverse FFT). Visibility to the
    // aggregation phase is guaranteed by the top-k barriers below.
    {
        const float4* V4 = (const float4*)(Vt + row);
        for (int t = tid; t < SEQ / 4; t += 256) {
            const float4 v = V4[t];
            const int b0 = PADF(4 * t);
            im[b0] = v.x; im[b0 + 1] = v.y; im[b0 + 2] = v.z; im[b0 + 3] = v.w;
        }
    }

    // Top-8 selection (argmax x8; ties -> lower index, matching jax.lax.top_k).
    // Candidates cached in registers; winner poisoned in-register via the
    // broadcast dsel[it] with compile-time-unrolled indexing (no scratch).
    float vals[16];
#pragma unroll
    for (int j = 0; j < 16; ++j) {
        vals[j] = re[PADF(tid + (j << 8))];
    }
    for (int it = 0; it < TOPK; ++it) {
        float best = NEGINF;
        int bidx = 0;
#pragma unroll
        for (int j = 0; j < 16; ++j) {
            const int t = tid + (j << 8);
            if (vals[j] > best) {  // strict: keeps lowest index on ties
                best = vals[j];
                bidx = t;
            }
        }
#pragma unroll
        for (int off = 32; off > 0; off >>= 1) {
            const float ov = __shfl_down(best, off);
            const int oi = __shfl_down(bidx, off);
            if (ov > best || (ov == best && oi < bidx)) {
                best = ov;
                bidx = oi;
            }
        }
        if ((tid & 63) == 0) {
            sval[tid >> 6] = best;
            sidx[tid >> 6] = bidx;
        }
        __syncthreads();
        if (tid == 0) {
            float bv = sval[0];
            int bi2 = sidx[0];
#pragma unroll
            for (int w = 1; w < 4; ++w) {
                const float ov = sval[w];
                const int oi = sidx[w];
                if (ov > bv || (ov == bv && oi < bi2)) {
                    bv = ov;
                    bi2 = oi;
                }
            }
            wsel[it] = bv;
            dsel[it] = bi2;
        }
        __syncthreads();
        const int win = dsel[it];
#pragma unroll
        for (int j = 0; j < 16; ++j) {
            if (tid + (j << 8) == win) vals[j] = NEGINF;
        }
    }

    // Aggregation: out[t] = sum_k w_k * V[(t + delay_k) & (SEQ-1)].
    float w[TOPK];
    int dl[TOPK];
#pragma unroll
    for (int k = 0; k < TOPK; ++k) {
        w[k] = wsel[k];
        dl[k] = dsel[k];
    }
    for (int j = 0; j < SEQ / 256; ++j) {
        const int t = tid + (j << 8);
        float acc = 0.0f;
#pragma unroll
        for (int k = 0; k < TOPK; ++k) {
            acc += w[k] * im[PADF((t + dl[k]) & (SEQ - 1))];
        }
        Ot[row + t] = acc;
    }
}

extern "C" void kernel_launch(void* const* d_in, const int* in_sizes, int n_in,
                              void* d_out, int out_size, void* d_ws, size_t ws_size,
                              hipStream_t stream) {
    const float* Q = (const float*)d_in[0];
    const float* K = (const float*)d_in[1];
    const float* V = (const float*)d_in[2];
    float* out = (float*)d_out;

    const size_t n = (size_t)NB * ND * SEQ;  // 8388608 elements per tensor
    float* Qt = (float*)d_ws;  // [B*D, S]; also reused as Ot (safe aliasing)
    float* Kt = Qt + n;
    float* Vt = Kt + n;

    // [B,S,D] -> [B,D,S] for Q, K, V in one dispatch (64x64 float4 tiles).
    dim3 g1(ND / 64, SEQ / 64, 3 * NB);
    hipLaunchKernelGGL(transpose3_k, g1, dim3(256), 0, stream, Q, K, V, Qt, Kt, Vt);

    // Per-lane FFT correlation + top-k + aggregation. Ot aliases Qt.
    hipLaunchKernelGGL(corr_topk_agg_k, dim3(NB * ND), dim3(256), 0, stream,
                       Qt, Kt, Vt, Qt);

    // [B,D,S] -> [B,S,D]
    dim3 g3(SEQ / 64, ND / 64, NB);
    hipLaunchKernelGGL(transpose_back_k, g3, dim3(256), 0, stream, Qt, out);
}